// Round 1
// baseline (256.088 us; speedup 1.0000x reference)
//
#include <hip/hip_runtime.h>
#include <hip/hip_bf16.h>
#include <math.h>

#define Bn 4096
#define Dd 768
#define SC2 28.85390081777927f   // 20 * log2(e): logits kept in base-2 domain
#define EPSF 1e-6f
#define DG 4.8516519541e8f       // expf(20.0f): exact exp_ori diagonal

// ws layout (4-byte elements)
#define O_S      0        // 3*4096 row sums (ori_nodiag, gen, aug)
#define O_SMOA   12288    // same-masked (ori_nodiag + aug) sums
#define O_SMG    16384    // same-masked gen sums
#define ZERO_F   20480    // floats to zero (covers all atomic sums)
#define O_P      20480    // uint: total pairs (= sum cnt^2)
#define O_RM     20608    // uint2[4096]: {tg | rank<<8, rowSlotBase}
#define LIST_OFF   262144      // byte offset: LCAP uint4 pair entries {row,x0,x1,x2}
#define LCAP       (1u << 19)
#define NB_OFF     33554432    // byte offset: bf16 normalized rows on|gn|an

typedef __attribute__((ext_vector_type(8))) short sh8;
typedef __attribute__((ext_vector_type(4))) float f32x4;

#define AS1 __attribute__((address_space(1)))
#define AS3 __attribute__((address_space(3)))

static __device__ __forceinline__ void gl_lds16(const void* g, void* l) {
    __builtin_amdgcn_global_load_lds((const AS1 void*)g, (AS3 void*)l, 16, 0, 0);
}

static __device__ __forceinline__ unsigned short f2b(float f) {
    unsigned int u = __float_as_uint(f);
    unsigned int r = (u + 0x7fffu + ((u >> 16) & 1u)) >> 16;  // RNE
    return (unsigned short)r;
}

// ---- normalize rows, write bf16 ----
__global__ void norm_kernel(const float* f0, const float* f1, const float* f2, unsigned short* nb) {
    int r = blockIdx.x, m = blockIdx.y, tid = threadIdx.x;
    const float* src = (m == 0 ? f0 : (m == 1 ? f1 : f2)) + (size_t)r * Dd;
    float x0 = src[tid], x1 = src[tid + 256], x2 = src[tid + 512];
    float v = x0 * x0 + x1 * x1 + x2 * x2;
    #pragma unroll
    for (int off = 1; off < 64; off <<= 1) v += __shfl_xor(v, off);
    __shared__ float wr[4];
    if ((tid & 63) == 0) wr[tid >> 6] = v;
    __syncthreads();
    float inv = rsqrtf(wr[0] + wr[1] + wr[2] + wr[3]);
    unsigned short* dst = nb + ((size_t)m * Bn + r) * Dd;
    dst[tid] = f2b(x0 * inv);
    dst[tid + 256] = f2b(x1 * inv);
    dst[tid + 512] = f2b(x2 * inv);
}

// ---- single-block: zero accumulators + class sort (hist/scan/rank+slot) ----
__launch_bounds__(1024)
__global__ void sort_kernel(const int* tg, unsigned int* I, float* out) {
    float* F = (float*)I;
    __shared__ unsigned int h[128], pb[128], cur[128];
    int tid = threadIdx.x;
    for (int e = tid; e < ZERO_F; e += 1024) F[e] = 0.f;
    if (tid == 0) { out[0] = 0.f; out[1] = 0.f; }
    if (tid < 128) { h[tid] = 0; cur[tid] = 0; }
    __syncthreads();
    for (int e = tid; e < Bn; e += 1024) atomicAdd(&h[tg[e]], 1u);
    __syncthreads();
    if (tid < 128) pb[tid] = h[tid] * h[tid];
    __syncthreads();
    for (int s = 1; s < 128; s <<= 1) {
        unsigned int b = 0;
        if (tid < 128 && tid >= s) b = pb[tid - s];
        __syncthreads();
        if (tid < 128) pb[tid] += b;
        __syncthreads();
    }
    if (tid == 127) I[O_P] = pb[127];
    uint2* RM = (uint2*)(I + O_RM);
    for (int e = tid; e < Bn; e += 1024) {
        int c = tg[e];
        unsigned int r = atomicAdd(&cur[c], 1u);
        unsigned int n = h[c];
        RM[e] = make_uint2((unsigned)c | (r << 8), (pb[c] - n * n) + r * n);
    }
}

// ---- R14: 256x256 tile, BK=32, 8 waves, 4-deep LDS pipeline with COUNTED
// vmcnt (T3+T4) + raw s_barrier (no compiler vmcnt(0) drain), T5 setprio.
// Previous (R9/R13) structure was the m97-style 2-syncthreads loop: every
// barrier drained the global_load_lds queue -> MfmaUtil capped at ~24%.
// Here K-tile t+3 is staged while t computes; steady-state wait is
// vmcnt(8) (= 2 tiles of 4 gl_lds in flight), never 0 in the main loop.
// Single barrier per K-step is race-free: a wave reaches iteration kt's
// barrier only after its MFMAs of kt-1 issued (which required lgkm
// completion of its ds_reads), so buffer (kt-1)&3 == (kt+3)&3 is fully
// consumed by ALL waves once the barrier is passed; staging into it is safe.
// LDS swizzle (chunk ^= (row>>1)&3) unchanged from R9 - measured 0 conflicts.
__launch_bounds__(512, 2)
__global__ void gemm_rowsum(const unsigned short* nb, char* ws) {
    float* F = (float*)ws;
    const unsigned int* I = (const unsigned int*)ws;
    const uint2* RM = (const uint2*)(I + O_RM);
    int z = blockIdx.z;
    const unsigned short* Ag = nb;
    const unsigned short* Bg = nb + (size_t)z * Bn * Dd;
    int m0 = blockIdx.y * 256, n0 = blockIdx.x * 256;
    int tid = threadIdx.x, lane = tid & 63, wave = tid >> 6;
    int wm = (wave >> 2) * 128, wn = (wave & 3) * 64;   // 2x4 wave grid, 128x64 per wave
    int lid = lane & 15, q = lane >> 4;
    __shared__ __align__(16) unsigned short Asm[4][256 * 32];  // 4 bufs x 16 KB
    __shared__ __align__(16) unsigned short Bsm[4][256 * 32];  // 4 bufs x 16 KB

    // staging map: element e in [0,1024) -> row=e>>2 (256 rows), chunk=e&3.
    // LDS stays linear (gl_lds requirement); SOURCE chunk is pre-swizzled
    // with the same XOR the ds_read applies (both-sides-or-neither).
    int r0 = tid >> 2, c0 = tid & 3;
    int sg = (c0 ^ ((r0 >> 1) & 3)) * 8;
    const unsigned short* pA0 = Ag + (size_t)(m0 + r0) * Dd + sg;
    const unsigned short* pA1 = pA0 + (size_t)128 * Dd;   // rows 128..255: same XOR (row+128 keeps (row>>1)&3)
    const unsigned short* pB0 = Bg + (size_t)(n0 + r0) * Dd + sg;
    const unsigned short* pB1 = pB0 + (size_t)128 * Dd;

    f32x4 acc[8][4] = {};

    // prologue: stage K-tiles 0,1,2 into bufs 0,1,2 (12 gl_lds/wave in flight)
    #pragma unroll
    for (int p = 0; p < 3; ++p) {
        gl_lds16(pA0 + p * 32, &Asm[p][tid * 8]);
        gl_lds16(pA1 + p * 32, &Asm[p][(512 + tid) * 8]);
        gl_lds16(pB0 + p * 32, &Bsm[p][tid * 8]);
        gl_lds16(pB1 + p * 32, &Bsm[p][(512 + tid) * 8]);
    }
    pA0 += 96; pA1 += 96; pB0 += 96; pB1 += 96;   // point at K-tile 3

    for (int kt = 0; kt < 24; ++kt) {
        int buf = kt & 3;
        // own loads of tile kt are the oldest outstanding; after the wait +
        // barrier, tile kt is in LDS for every wave. Never vmcnt(0) mid-loop.
        if (kt < 22)       asm volatile("s_waitcnt vmcnt(8)" ::: "memory");
        else if (kt == 22) asm volatile("s_waitcnt vmcnt(4)" ::: "memory");
        else               asm volatile("s_waitcnt vmcnt(0)" ::: "memory");
        __builtin_amdgcn_sched_barrier(0);
        __builtin_amdgcn_s_barrier();          // raw: no implicit vmcnt(0) drain
        __builtin_amdgcn_sched_barrier(0);
        if (kt < 21) {
            // stage tile kt+3 into buf (kt+3)&3 == (kt-1)&3 (fully consumed)
            int nbuf = (kt + 3) & 3;
            gl_lds16(pA0, &Asm[nbuf][tid * 8]);
            gl_lds16(pA1, &Asm[nbuf][(512 + tid) * 8]);
            gl_lds16(pB0, &Bsm[nbuf][tid * 8]);
            gl_lds16(pB1, &Bsm[nbuf][(512 + tid) * 8]);
            pA0 += 32; pA1 += 32; pB0 += 32; pB1 += 32;
        }
        sh8 af[8], bf[4];
        #pragma unroll
        for (int i = 0; i < 8; ++i) {
            int r = wm + i * 16 + lid;
            af[i] = *(const sh8*)&Asm[buf][r * 32 + ((q ^ ((r >> 1) & 3)) * 8)];
        }
        #pragma unroll
        for (int j = 0; j < 4; ++j) {
            int r = wn + j * 16 + lid;
            bf[j] = *(const sh8*)&Bsm[buf][r * 32 + ((q ^ ((r >> 1) & 3)) * 8)];
        }
        __builtin_amdgcn_s_setprio(1);
        #pragma unroll
        for (int i = 0; i < 8; ++i)
            #pragma unroll
            for (int j = 0; j < 4; ++j)
                acc[i][j] = __builtin_amdgcn_mfma_f32_16x16x32_bf16(af[i], bf[j], acc[i][j], 0, 0, 0);
        __builtin_amdgcn_s_setprio(0);
    }

    // ---- epilogue: row sum, masked sum, pair-list word stores ----
    uint2 rmc[4];
    #pragma unroll
    for (int j = 0; j < 4; ++j) rmc[j] = RM[n0 + wn + j * 16 + lid];
    int smoff = (z == 1) ? O_SMG : O_SMOA;
    unsigned int* Lw = (unsigned int*)(ws + LIST_OFF);
    #pragma unroll
    for (int i = 0; i < 8; ++i)
        #pragma unroll
        for (int reg = 0; reg < 4; ++reg) {
            int grow = m0 + wm + i * 16 + q * 4 + reg;
            uint2 rm = RM[grow];
            unsigned int trow = rm.x & 255u, rsb = rm.y;
            float rs = 0.f, ms = 0.f;
            #pragma unroll
            for (int j = 0; j < 4; ++j) {
                int gcol = n0 + wn + j * 16 + lid;
                float x = acc[i][j][reg] * SC2;
                float e = exp2f(x);
                if (z == 0 && gcol == grow) e = 0.f;
                rs += e;
                if ((rmc[j].x & 255u) == trow) {
                    ms += e;
                    unsigned int slot = rsb + (rmc[j].x >> 8);
                    if (slot < LCAP) {
                        if (z == 0) {
                            Lw[slot * 4 + 0] = (unsigned)grow;
                            Lw[slot * 4 + 1] = __float_as_uint(x);
                        } else {
                            Lw[slot * 4 + 1 + z] = __float_as_uint(x);
                        }
                    }
                }
            }
            #pragma unroll
            for (int off = 1; off < 16; off <<= 1) {
                rs += __shfl_xor(rs, off);
                ms += __shfl_xor(ms, off);
            }
            if (lid == 0) {
                atomicAdd(&F[O_S + z * Bn + grow], rs);
                atomicAdd(&F[smoff + grow], ms);
            }
        }
}

// ---- flat loss pass: inline denominators, scaled atomic into d_out ----
__launch_bounds__(256)
__global__ void loss_kernel(char* ws, float* out) {
    float* F = (float*)ws;
    const unsigned int* I = (const unsigned int*)ws;
    const uint4* L = (const uint4*)(ws + LIST_OFF);
    unsigned int n = I[O_P]; if (n > LCAP) n = LCAP;
    float a0 = 0.f, a1 = 0.f;
    unsigned int stride = gridDim.x * 256;
    for (unsigned int idx = blockIdx.x * 256 + threadIdx.x; idx < n; idx += stride) {
        uint4 en = L[idx];
        int i = (int)en.x;
        float son = F[O_S + i], sgen = F[O_S + Bn + i], saug = F[O_S + 2 * Bn + i];
        float dco = (son + saug - F[O_SMOA + i]) + sgen + EPSF;
        float dad = (sgen - F[O_SMG + i]) + saug + son + DG + EPSF;
        float eo = exp2f(__uint_as_float(en.y));
        float eg = exp2f(__uint_as_float(en.z));
        float ea = exp2f(__uint_as_float(en.w));
        a0 += -__logf(eg / (eg + dad) + EPSF);
        a1 += -__logf(eo / (eo + dco) + EPSF) - __logf(ea / (ea + dco) + EPSF);
    }
    #pragma unroll
    for (int off = 1; off < 64; off <<= 1) { a0 += __shfl_xor(a0, off); a1 += __shfl_xor(a1, off); }
    __shared__ float r0[4], r1[4];
    int tid = threadIdx.x;
    if ((tid & 63) == 0) { r0[tid >> 6] = a0; r1[tid >> 6] = a1; }
    __syncthreads();
    if (tid == 0) {
        atomicAdd(&out[0], (r0[0] + r0[1] + r0[2] + r0[3]) * (1.0f / Bn));  // ad_loss
        atomicAdd(&out[1], (r1[0] + r1[1] + r1[2] + r1[3]) * (1.0f / Bn));  // co_loss
    }
}

extern "C" void kernel_launch(void* const* d_in, const int* in_sizes, int n_in,
                              void* d_out, int out_size, void* d_ws, size_t ws_size,
                              hipStream_t stream) {
    const float* f0 = (const float*)d_in[0];
    const float* f1 = (const float*)d_in[1];
    const float* f2 = (const float*)d_in[2];
    const int* tg = (const int*)d_in[3];
    char* ws = (char*)d_ws;
    unsigned int* I = (unsigned int*)d_ws;
    unsigned short* nb = (unsigned short*)(ws + NB_OFF);
    float* out = (float*)d_out;

    norm_kernel<<<dim3(Bn, 3), 256, 0, stream>>>(f0, f1, f2, nb);
    sort_kernel<<<1, 1024, 0, stream>>>(tg, I, out);
    gemm_rowsum<<<dim3(16, 16, 3), 512, 0, stream>>>(nb, ws);
    loss_kernel<<<256, 256, 0, stream>>>(ws, out);
}

// Round 2
// 234.118 us; speedup vs baseline: 1.0938x; 1.0938x over previous
//
#include <hip/hip_runtime.h>
#include <hip/hip_bf16.h>
#include <math.h>

#define Bn 4096
#define Dd 768
#define SC2 28.85390081777927f   // 20 * log2(e): logits kept in base-2 domain
#define EPSF 1e-6f
#define DG 4.8516519541e8f       // expf(20.0f): exact exp_ori diagonal

// ws layout (4-byte elements)
#define O_S      0        // 3*4096 row sums (ori_nodiag, gen, aug)
#define O_SMOA   12288    // same-masked (ori_nodiag + aug) sums
#define O_SMG    16384    // same-masked gen sums
#define ZERO_F   20480    // floats to zero (covers all atomic sums)
#define O_P      20480    // uint: total pairs (= sum cnt^2)
#define O_RM     20608    // uint2[4096]: {tg | rank<<8, rowSlotBase}
#define LIST_OFF   262144      // byte offset: LCAP uint4 pair entries {row,x0,x1,x2}
#define LCAP       (1u << 19)
#define NB_OFF     33554432    // byte offset: bf16 normalized rows on|gn|an

typedef __attribute__((ext_vector_type(8))) short sh8;
typedef __attribute__((ext_vector_type(4))) float f32x4;

#define AS1 __attribute__((address_space(1)))
#define AS3 __attribute__((address_space(3)))

static __device__ __forceinline__ void gl_lds16(const void* g, void* l) {
    __builtin_amdgcn_global_load_lds((const AS1 void*)g, (AS3 void*)l, 16, 0, 0);
}

static __device__ __forceinline__ unsigned short f2b(float f) {
    unsigned int u = __float_as_uint(f);
    unsigned int r = (u + 0x7fffu + ((u >> 16) & 1u)) >> 16;  // RNE
    return (unsigned short)r;
}

// ---- normalize rows, write bf16 ----
__global__ void norm_kernel(const float* f0, const float* f1, const float* f2, unsigned short* nb) {
    int r = blockIdx.x, m = blockIdx.y, tid = threadIdx.x;
    const float* src = (m == 0 ? f0 : (m == 1 ? f1 : f2)) + (size_t)r * Dd;
    float x0 = src[tid], x1 = src[tid + 256], x2 = src[tid + 512];
    float v = x0 * x0 + x1 * x1 + x2 * x2;
    #pragma unroll
    for (int off = 1; off < 64; off <<= 1) v += __shfl_xor(v, off);
    __shared__ float wr[4];
    if ((tid & 63) == 0) wr[tid >> 6] = v;
    __syncthreads();
    float inv = rsqrtf(wr[0] + wr[1] + wr[2] + wr[3]);
    unsigned short* dst = nb + ((size_t)m * Bn + r) * Dd;
    dst[tid] = f2b(x0 * inv);
    dst[tid + 256] = f2b(x1 * inv);
    dst[tid + 512] = f2b(x2 * inv);
}

// ---- single-block: zero accumulators + class sort (hist/scan/rank+slot) ----
__launch_bounds__(1024)
__global__ void sort_kernel(const int* tg, unsigned int* I, float* out) {
    float* F = (float*)I;
    __shared__ unsigned int h[128], pb[128], cur[128];
    int tid = threadIdx.x;
    for (int e = tid; e < ZERO_F; e += 1024) F[e] = 0.f;
    if (tid == 0) { out[0] = 0.f; out[1] = 0.f; }
    if (tid < 128) { h[tid] = 0; cur[tid] = 0; }
    __syncthreads();
    for (int e = tid; e < Bn; e += 1024) atomicAdd(&h[tg[e]], 1u);
    __syncthreads();
    if (tid < 128) pb[tid] = h[tid] * h[tid];
    __syncthreads();
    for (int s = 1; s < 128; s <<= 1) {
        unsigned int b = 0;
        if (tid < 128 && tid >= s) b = pb[tid - s];
        __syncthreads();
        if (tid < 128) pb[tid] += b;
        __syncthreads();
    }
    if (tid == 127) I[O_P] = pb[127];
    uint2* RM = (uint2*)(I + O_RM);
    for (int e = tid; e < Bn; e += 1024) {
        int c = tg[e];
        unsigned int r = atomicAdd(&cur[c], 1u);
        unsigned int n = h[c];
        RM[e] = make_uint2((unsigned)c | (r << 8), (pb[c] - n * n) + r * n);
    }
}

// ======================= R15: fine-phase 8-phase-style schedule ==========
// 256x256 tile, BK=64, 12 K-tiles = 12 windows x 4 phases. Each phase:
// {ds-read subtile || stage one 16KB group (2 gl_lds)} -> vmcnt(6) ->
// s_barrier -> 16 MFMA (setprio) -> s_barrier. Register reuse: each LDS
// region is ds-read in exactly ONE phase (A-half@p1/p3, B-half@p1/p2), so
// every stage overwrites a region retired >=1 end-barrier earlier.
// Stage->read gap >= 4 phases; vmcnt(6)/phase guarantees >=4-phase-old
// loads landed (steady in-flight = 3 groups = 6 loads). Tile t in buf[t&1]:
// window w stages t(w+1) A13@p1, B1@p2 (other parity), t(w+2) A02@p3,
// B0@p4 (same parity as current - regions retired at p1's end-barrier).
// Swizzle: chunk' = chunk ^ (row&7) on both stage-source and ds_read.

static __device__ __forceinline__ void ld_af(const unsigned short* Lb, int wm, int rh,
                                             int lid, int c0, int c1, sh8 af[4][2]) {
    #pragma unroll
    for (int ii = 0; ii < 4; ++ii) {
        int r = (wm + rh * 64 + ii * 16 + lid) * 64;
        af[ii][0] = *(const sh8*)&Lb[r + c0];
        af[ii][1] = *(const sh8*)&Lb[r + c1];
    }
}
static __device__ __forceinline__ void ld_bf(const unsigned short* Lb, int wn, int ch,
                                             int lid, int c0, int c1, sh8 bf[2][2]) {
    #pragma unroll
    for (int jj = 0; jj < 2; ++jj) {
        int r = (wn + ch * 32 + jj * 16 + lid) * 64;
        bf[jj][0] = *(const sh8*)&Lb[r + c0];
        bf[jj][1] = *(const sh8*)&Lb[r + c1];
    }
}
static __device__ __forceinline__ void mfma_q(f32x4 acc[8][4], const sh8 af[4][2],
                                              const sh8 bf[2][2], int rh, int ch) {
    #pragma unroll
    for (int ii = 0; ii < 4; ++ii)
        #pragma unroll
        for (int jj = 0; jj < 2; ++jj) {
            acc[rh*4+ii][ch*2+jj] = __builtin_amdgcn_mfma_f32_16x16x32_bf16(
                af[ii][0], bf[jj][0], acc[rh*4+ii][ch*2+jj], 0, 0, 0);
            acc[rh*4+ii][ch*2+jj] = __builtin_amdgcn_mfma_f32_16x16x32_bf16(
                af[ii][1], bf[jj][1], acc[rh*4+ii][ch*2+jj], 0, 0, 0);
        }
}

#define ST_A02(P, L) { gl_lds16((P), &(L)[dA]); gl_lds16((P) + (size_t)128*Dd, &(L)[2*4096 + dA]); }
#define ST_A13(P, L) { gl_lds16((P) + (size_t)64*Dd, &(L)[4096 + dA]); gl_lds16((P) + (size_t)192*Dd, &(L)[3*4096 + dA]); }
#define ST_B0(P, L)  { gl_lds16((P), &(L)[dB]); gl_lds16((P) + (size_t)128*Dd, &(L)[8192 + dB]); }
#define ST_B1(P, L)  { gl_lds16((P), &(L)[2048 + dB]); gl_lds16((P) + (size_t)128*Dd, &(L)[2048 + 8192 + dB]); }

#define PSYNC6 { asm volatile("s_waitcnt vmcnt(6)" ::: "memory"); \
    __builtin_amdgcn_sched_barrier(0); __builtin_amdgcn_s_barrier(); __builtin_amdgcn_sched_barrier(0); }
#define EBAR { __builtin_amdgcn_sched_barrier(0); __builtin_amdgcn_s_barrier(); __builtin_amdgcn_sched_barrier(0); }

__launch_bounds__(512, 2)
__global__ void gemm_rowsum(const unsigned short* nb, char* ws) {
    float* F = (float*)ws;
    const unsigned int* I = (const unsigned int*)ws;
    const uint2* RM = (const uint2*)(I + O_RM);
    int z = blockIdx.z;
    const unsigned short* Ag = nb;
    const unsigned short* Bg = nb + (size_t)z * Bn * Dd;
    int m0 = blockIdx.y * 256, n0 = blockIdx.x * 256;
    int tid = threadIdx.x, lane = tid & 63, wave = tid >> 6;
    int wm = (wave >> 2) * 128, wn = (wave & 3) * 64;   // 2x4 wave grid, 128x64/wave
    int lid = lane & 15, q = lane >> 4;

    __shared__ __align__(16) unsigned short A_s[2][256 * 64];  // 2 x 32 KB
    __shared__ __align__(16) unsigned short B_s[2][256 * 64];  // 2 x 32 KB

    // ---- staging geometry: linear LDS dest (uniform+lane*16), pre-swizzled src
    int loc = tid >> 3;
    int cs = ((tid & 7) ^ (loc & 7)) * 8;           // swizzled source chunk (elems)
    int rB = (loc & 31) + (loc >> 5) * 64;          // B ch-band row pattern
    const unsigned short* pA02 = Ag + (size_t)(m0 + loc) * Dd + cs + 128;      // tile 2
    const unsigned short* pA13 = Ag + (size_t)(m0 + loc) * Dd + cs + 64;       // tile 1
    const unsigned short* pB0  = Bg + (size_t)(n0 + rB) * Dd + cs + 128;       // tile 2
    const unsigned short* pB1  = Bg + (size_t)(n0 + rB + 32) * Dd + cs + 64;   // tile 1
    int dA = tid * 8;
    int dB = rB * 64 + (tid & 7) * 8;

    // frag-read swizzle constants (row&7 == lid&7 for all frag rows)
    int cswz0 = (q ^ (lid & 7)) * 8;
    int cswz1 = ((4 + q) ^ (lid & 7)) * 8;

    sh8 af[4][2], bf0[2][2], bf1[2][2];
    f32x4 acc[8][4] = {};

    // ---- prologue: t0 full + t1 {A02,B0}; 12 loads; first 4 = t0 p1-data
    ST_A02(pA02 - 128, A_s[0]);
    ST_B0 (pB0  - 128, B_s[0]);
    ST_A13(pA13 -  64, A_s[0]);
    ST_B1 (pB1  -  64, B_s[0]);
    ST_A02(pA02 -  64, A_s[1]);
    ST_B0 (pB0  -  64, B_s[1]);
    asm volatile("s_waitcnt vmcnt(8)" ::: "memory");
    __builtin_amdgcn_sched_barrier(0);
    __builtin_amdgcn_s_barrier();
    __builtin_amdgcn_sched_barrier(0);

    for (int w = 0; w < 10; ++w) {
        unsigned short* Ab  = A_s[w & 1];
        unsigned short* Bb  = B_s[w & 1];
        unsigned short* Abn = A_s[(w & 1) ^ 1];
        unsigned short* Bbn = B_s[(w & 1) ^ 1];
        // phase 1 (rh0,ch0): reads A02+B0 of tile w; stage t(w+1).A13
        ld_af(Ab, wm, 0, lid, cswz0, cswz1, af);
        ld_bf(Bb, wn, 0, lid, cswz0, cswz1, bf0);
        ST_A13(pA13, Abn);
        PSYNC6;
        __builtin_amdgcn_s_setprio(1);
        mfma_q(acc, af, bf0, 0, 0);
        __builtin_amdgcn_s_setprio(0);
        EBAR;
        // phase 2 (rh0,ch1): reads B1; stage t(w+1).B1
        ld_bf(Bb, wn, 1, lid, cswz0, cswz1, bf1);
        ST_B1(pB1, Bbn);
        PSYNC6;
        __builtin_amdgcn_s_setprio(1);
        mfma_q(acc, af, bf1, 0, 1);
        __builtin_amdgcn_s_setprio(0);
        EBAR;
        // phase 3 (rh1,ch0): reads A13; stage t(w+2).A02 (region retired @p1)
        ld_af(Ab, wm, 1, lid, cswz0, cswz1, af);
        ST_A02(pA02, Ab);
        PSYNC6;
        __builtin_amdgcn_s_setprio(1);
        mfma_q(acc, af, bf0, 1, 0);
        __builtin_amdgcn_s_setprio(0);
        EBAR;
        // phase 4 (rh1,ch1): no reads; stage t(w+2).B0 (region retired @p1)
        ST_B0(pB0, Bb);
        PSYNC6;
        __builtin_amdgcn_s_setprio(1);
        mfma_q(acc, af, bf1, 1, 1);
        __builtin_amdgcn_s_setprio(0);
        EBAR;
        pA02 += 64; pA13 += 64; pB0 += 64; pB1 += 64;
    }
    // ---- window 10 (buf0): stage only t11.{A13,B1}; drain at p4
    {
        unsigned short* Ab  = A_s[0];
        unsigned short* Bb  = B_s[0];
        unsigned short* Abn = A_s[1];
        unsigned short* Bbn = B_s[1];
        ld_af(Ab, wm, 0, lid, cswz0, cswz1, af);
        ld_bf(Bb, wn, 0, lid, cswz0, cswz1, bf0);
        ST_A13(pA13, Abn);
        PSYNC6;
        mfma_q(acc, af, bf0, 0, 0);
        EBAR;
        ld_bf(Bb, wn, 1, lid, cswz0, cswz1, bf1);
        ST_B1(pB1, Bbn);
        PSYNC6;
        mfma_q(acc, af, bf1, 0, 1);
        EBAR;
        ld_af(Ab, wm, 1, lid, cswz0, cswz1, af);
        PSYNC6;
        mfma_q(acc, af, bf0, 1, 0);
        EBAR;
        asm volatile("s_waitcnt vmcnt(0)" ::: "memory");   // endgame drain (publishes t11)
        __builtin_amdgcn_sched_barrier(0);
        __builtin_amdgcn_s_barrier();
        __builtin_amdgcn_sched_barrier(0);
        mfma_q(acc, af, bf1, 1, 1);
    }
    // ---- window 11 (buf1): everything resident+published, no sync needed
    {
        unsigned short* Ab = A_s[1];
        unsigned short* Bb = B_s[1];
        ld_af(Ab, wm, 0, lid, cswz0, cswz1, af);
        ld_bf(Bb, wn, 0, lid, cswz0, cswz1, bf0);
        mfma_q(acc, af, bf0, 0, 0);
        ld_bf(Bb, wn, 1, lid, cswz0, cswz1, bf1);
        mfma_q(acc, af, bf1, 0, 1);
        ld_af(Ab, wm, 1, lid, cswz0, cswz1, af);
        mfma_q(acc, af, bf0, 1, 0);
        mfma_q(acc, af, bf1, 1, 1);
    }

    // ---- epilogue: row sum, masked sum, pair-list word stores ----
    uint2 rmc[4];
    #pragma unroll
    for (int j = 0; j < 4; ++j) rmc[j] = RM[n0 + wn + j * 16 + lid];
    int smoff = (z == 1) ? O_SMG : O_SMOA;
    unsigned int* Lw = (unsigned int*)(ws + LIST_OFF);
    #pragma unroll
    for (int i = 0; i < 8; ++i)
        #pragma unroll
        for (int reg = 0; reg < 4; ++reg) {
            int grow = m0 + wm + i * 16 + q * 4 + reg;
            uint2 rm = RM[grow];
            unsigned int trow = rm.x & 255u, rsb = rm.y;
            float rs = 0.f, ms = 0.f;
            #pragma unroll
            for (int j = 0; j < 4; ++j) {
                int gcol = n0 + wn + j * 16 + lid;
                float x = acc[i][j][reg] * SC2;
                float e = exp2f(x);
                if (z == 0 && gcol == grow) e = 0.f;
                rs += e;
                if ((rmc[j].x & 255u) == trow) {
                    ms += e;
                    unsigned int slot = rsb + (rmc[j].x >> 8);
                    if (slot < LCAP) {
                        if (z == 0) {
                            Lw[slot * 4 + 0] = (unsigned)grow;
                            Lw[slot * 4 + 1] = __float_as_uint(x);
                        } else {
                            Lw[slot * 4 + 1 + z] = __float_as_uint(x);
                        }
                    }
                }
            }
            #pragma unroll
            for (int off = 1; off < 16; off <<= 1) {
                rs += __shfl_xor(rs, off);
                ms += __shfl_xor(ms, off);
            }
            if (lid == 0) {
                atomicAdd(&F[O_S + z * Bn + grow], rs);
                atomicAdd(&F[smoff + grow], ms);
            }
        }
}

// ---- flat loss pass: inline denominators, scaled atomic into d_out ----
__launch_bounds__(256)
__global__ void loss_kernel(char* ws, float* out) {
    float* F = (float*)ws;
    const unsigned int* I = (const unsigned int*)ws;
    const uint4* L = (const uint4*)(ws + LIST_OFF);
    unsigned int n = I[O_P]; if (n > LCAP) n = LCAP;
    float a0 = 0.f, a1 = 0.f;
    unsigned int stride = gridDim.x * 256;
    for (unsigned int idx = blockIdx.x * 256 + threadIdx.x; idx < n; idx += stride) {
        uint4 en = L[idx];
        int i = (int)en.x;
        float son = F[O_S + i], sgen = F[O_S + Bn + i], saug = F[O_S + 2 * Bn + i];
        float dco = (son + saug - F[O_SMOA + i]) + sgen + EPSF;
        float dad = (sgen - F[O_SMG + i]) + saug + son + DG + EPSF;
        float eo = exp2f(__uint_as_float(en.y));
        float eg = exp2f(__uint_as_float(en.z));
        float ea = exp2f(__uint_as_float(en.w));
        a0 += -__logf(eg / (eg + dad) + EPSF);
        a1 += -__logf(eo / (eo + dco) + EPSF) - __logf(ea / (ea + dco) + EPSF);
    }
    #pragma unroll
    for (int off = 1; off < 64; off <<= 1) { a0 += __shfl_xor(a0, off); a1 += __shfl_xor(a1, off); }
    __shared__ float r0[4], r1[4];
    int tid = threadIdx.x;
    if ((tid & 63) == 0) { r0[tid >> 6] = a0; r1[tid >> 6] = a1; }
    __syncthreads();
    if (tid == 0) {
        atomicAdd(&out[0], (r0[0] + r0[1] + r0[2] + r0[3]) * (1.0f / Bn));  // ad_loss
        atomicAdd(&out[1], (r1[0] + r1[1] + r1[2] + r1[3]) * (1.0f / Bn));  // co_loss
    }
}

extern "C" void kernel_launch(void* const* d_in, const int* in_sizes, int n_in,
                              void* d_out, int out_size, void* d_ws, size_t ws_size,
                              hipStream_t stream) {
    const float* f0 = (const float*)d_in[0];
    const float* f1 = (const float*)d_in[1];
    const float* f2 = (const float*)d_in[2];
    const int* tg = (const int*)d_in[3];
    char* ws = (char*)d_ws;
    unsigned int* I = (unsigned int*)d_ws;
    unsigned short* nb = (unsigned short*)(ws + NB_OFF);
    float* out = (float*)d_out;

    norm_kernel<<<dim3(Bn, 3), 256, 0, stream>>>(f0, f1, f2, nb);
    sort_kernel<<<1, 1024, 0, stream>>>(tg, I, out);
    gemm_rowsum<<<dim3(16, 16, 3), 512, 0, stream>>>(nb, ws);
    loss_kernel<<<256, 256, 0, stream>>>(ws, out);
}

// Round 3
// 205.386 us; speedup vs baseline: 1.2469x; 1.1399x over previous
//
#include <hip/hip_runtime.h>
#include <hip/hip_bf16.h>
#include <math.h>

#define Bn 4096
#define Dd 768
#define SC2 28.85390081777927f   // 20 * log2(e): logits kept in base-2 domain
#define EPSF 1e-6f
#define DG 4.8516519541e8f       // expf(20.0f): exact exp_ori diagonal

// ws layout (4-byte elements)
#define O_S      0        // 3*4096 row sums (ori_nodiag, gen, aug)
#define O_SMOA   12288    // same-masked (ori_nodiag + aug) sums
#define O_SMG    16384    // same-masked gen sums
#define ZERO_F   20480    // floats to zero (covers all atomic sums)
#define O_P      20480    // uint: total pairs (= sum cnt^2)
#define O_RM     20608    // uint2[4096]: {tg | rank<<8, rowSlotBase}
#define LIST_OFF   262144      // byte offset: LCAP uint4 pair entries {row,x0,x1,x2}
#define LCAP       (1u << 19)
#define NB_OFF     33554432    // byte offset: bf16 normalized rows on|gn|an

typedef __attribute__((ext_vector_type(8))) short sh8;
typedef __attribute__((ext_vector_type(4))) float f32x4;

#define AS1 __attribute__((address_space(1)))
#define AS3 __attribute__((address_space(3)))

static __device__ __forceinline__ void gl_lds16(const void* g, void* l) {
    __builtin_amdgcn_global_load_lds((const AS1 void*)g, (AS3 void*)l, 16, 0, 0);
}

static __device__ __forceinline__ unsigned short f2b(float f) {
    unsigned int u = __float_as_uint(f);
    unsigned int r = (u + 0x7fffu + ((u >> 16) & 1u)) >> 16;  // RNE
    return (unsigned short)r;
}

// ---- normalize rows, write bf16 ----
__global__ void norm_kernel(const float* f0, const float* f1, const float* f2, unsigned short* nb) {
    int r = blockIdx.x, m = blockIdx.y, tid = threadIdx.x;
    const float* src = (m == 0 ? f0 : (m == 1 ? f1 : f2)) + (size_t)r * Dd;
    float x0 = src[tid], x1 = src[tid + 256], x2 = src[tid + 512];
    float v = x0 * x0 + x1 * x1 + x2 * x2;
    #pragma unroll
    for (int off = 1; off < 64; off <<= 1) v += __shfl_xor(v, off);
    __shared__ float wr[4];
    if ((tid & 63) == 0) wr[tid >> 6] = v;
    __syncthreads();
    float inv = rsqrtf(wr[0] + wr[1] + wr[2] + wr[3]);
    unsigned short* dst = nb + ((size_t)m * Bn + r) * Dd;
    dst[tid] = f2b(x0 * inv);
    dst[tid + 256] = f2b(x1 * inv);
    dst[tid + 512] = f2b(x2 * inv);
}

// ---- single-block: zero accumulators + class sort (hist/scan/rank+slot) ----
__launch_bounds__(1024)
__global__ void sort_kernel(const int* tg, unsigned int* I, float* out) {
    float* F = (float*)I;
    __shared__ unsigned int h[128], pb[128], cur[128];
    int tid = threadIdx.x;
    for (int e = tid; e < ZERO_F; e += 1024) F[e] = 0.f;
    if (tid == 0) { out[0] = 0.f; out[1] = 0.f; }
    if (tid < 128) { h[tid] = 0; cur[tid] = 0; }
    __syncthreads();
    for (int e = tid; e < Bn; e += 1024) atomicAdd(&h[tg[e]], 1u);
    __syncthreads();
    if (tid < 128) pb[tid] = h[tid] * h[tid];
    __syncthreads();
    for (int s = 1; s < 128; s <<= 1) {
        unsigned int b = 0;
        if (tid < 128 && tid >= s) b = pb[tid - s];
        __syncthreads();
        if (tid < 128) pb[tid] += b;
        __syncthreads();
    }
    if (tid == 127) I[O_P] = pb[127];
    uint2* RM = (uint2*)(I + O_RM);
    for (int e = tid; e < Bn; e += 1024) {
        int c = tg[e];
        unsigned int r = atomicAdd(&cur[c], 1u);
        unsigned int n = h[c];
        RM[e] = make_uint2((unsigned)c | (r << 8), (pb[c] - n * n) + r * n);
    }
}

// ======================= R16: 3-z FUSED m97-loop =========================
// All three GEMMs (ori/gen/aug) share the same A operand. Fuse z into one
// kernel: per K-tile, stage A once + three B tiles, run 48 MFMA/wave per
// barrier-pair (3x the m97 ratio) into three acc sets. Proven R9 skeleton
// (single-buffer, 2 syncthreads/kt, chunk^((row>>1)&3) swizzle — measured
// 0 conflicts) + 2 blocks/CU residency (32KB LDS, <=256 regs). The R14/R15
// fine-phase 256^2 experiments both lost to this at K=768 (no amortization;
// m248 showed the 8-phase template itself only reaches ~34% at short K).
// Epilogue fuses too: one uint4 list store per pair (was 3 scattered
// words), 5 atomics (was 6), grid 3072 -> 1024 blocks.
__launch_bounds__(256, 2)
__global__ void gemm_rowsum(const unsigned short* nb, char* ws) {
    float* F = (float*)ws;
    const unsigned int* I = (const unsigned int*)ws;
    const uint2* RM = (const uint2*)(I + O_RM);
    // XCD-aware swizzle (1024 % 8 == 0 -> simple bijection): each XCD gets
    // 128 consecutive tiles = 4 m-rows x 32 n -> A panels L2-resident.
    int bid = blockIdx.x;
    int sw = (bid & 7) * 128 + (bid >> 3);
    int m0 = (sw >> 5) * 128, n0 = (sw & 31) * 128;
    int tid = threadIdx.x, lane = tid & 63, wave = tid >> 6;
    int wm = (wave >> 1) * 64, wn = (wave & 1) * 64;   // 2x2 waves, 64x64/wave/z
    int lid = lane & 15, q = lane >> 4;
    __shared__ __align__(16) unsigned short Asm[128 * 32];      // 8 KB
    __shared__ __align__(16) unsigned short Bsm[3][128 * 32];   // 24 KB

    // staging: thread -> (row = tid>>2, chunk = tid&3), rows 0..63 in load0,
    // 64..127 in load1 (same swizzle: (row+64)>>1 & 3 unchanged). LDS linear,
    // source chunk pre-swizzled (both-sides-or-neither rule).
    int row0 = tid >> 2, ch = tid & 3;
    int cs = (ch ^ ((row0 >> 1) & 3)) * 8;
    const unsigned short* gA  = nb + (size_t)(m0 + row0) * Dd + cs;
    const unsigned short* gB0 = nb + (size_t)(n0 + row0) * Dd + cs;
    const unsigned short* gB1 = gB0 + (size_t)Bn * Dd;
    const unsigned short* gB2 = gB1 + (size_t)Bn * Dd;
    unsigned short* lA0 = &Asm[tid * 8];
    unsigned short* lA1 = &Asm[(tid + 256) * 8];

    // frag-read swizzle: r = wm|wn + i*16 + lid -> (r>>1)&3 == (lid>>1)&3
    int cswz = (q ^ ((lid >> 1) & 3)) * 8;

    f32x4 a0[4][4] = {}, a1[4][4] = {}, a2[4][4] = {};

    for (int kt = 0; kt < 24; ++kt) {
        const unsigned short* pa  = gA  + kt * 32;
        const unsigned short* pb0 = gB0 + kt * 32;
        const unsigned short* pb1 = gB1 + kt * 32;
        const unsigned short* pb2 = gB2 + kt * 32;
        __syncthreads();
        gl_lds16(pa, lA0);
        gl_lds16(pa + (size_t)64 * Dd, lA1);
        gl_lds16(pb0, &Bsm[0][tid * 8]);
        gl_lds16(pb0 + (size_t)64 * Dd, &Bsm[0][(tid + 256) * 8]);
        gl_lds16(pb1, &Bsm[1][tid * 8]);
        gl_lds16(pb1 + (size_t)64 * Dd, &Bsm[1][(tid + 256) * 8]);
        gl_lds16(pb2, &Bsm[2][tid * 8]);
        gl_lds16(pb2 + (size_t)64 * Dd, &Bsm[2][(tid + 256) * 8]);
        __syncthreads();
        sh8 af[4];
        #pragma unroll
        for (int i = 0; i < 4; ++i)
            af[i] = *(const sh8*)&Asm[(wm + i * 16 + lid) * 32 + cswz];
        {
            sh8 bf[4];
            #pragma unroll
            for (int j = 0; j < 4; ++j)
                bf[j] = *(const sh8*)&Bsm[0][(wn + j * 16 + lid) * 32 + cswz];
            #pragma unroll
            for (int i = 0; i < 4; ++i)
                #pragma unroll
                for (int j = 0; j < 4; ++j)
                    a0[i][j] = __builtin_amdgcn_mfma_f32_16x16x32_bf16(af[i], bf[j], a0[i][j], 0, 0, 0);
        }
        {
            sh8 bf[4];
            #pragma unroll
            for (int j = 0; j < 4; ++j)
                bf[j] = *(const sh8*)&Bsm[1][(wn + j * 16 + lid) * 32 + cswz];
            #pragma unroll
            for (int i = 0; i < 4; ++i)
                #pragma unroll
                for (int j = 0; j < 4; ++j)
                    a1[i][j] = __builtin_amdgcn_mfma_f32_16x16x32_bf16(af[i], bf[j], a1[i][j], 0, 0, 0);
        }
        {
            sh8 bf[4];
            #pragma unroll
            for (int j = 0; j < 4; ++j)
                bf[j] = *(const sh8*)&Bsm[2][(wn + j * 16 + lid) * 32 + cswz];
            #pragma unroll
            for (int i = 0; i < 4; ++i)
                #pragma unroll
                for (int j = 0; j < 4; ++j)
                    a2[i][j] = __builtin_amdgcn_mfma_f32_16x16x32_bf16(af[i], bf[j], a2[i][j], 0, 0, 0);
        }
    }

    // ---- fused epilogue: 3 row sums, 2 masked sums, single uint4 pair store
    uint2 rmc[4];
    #pragma unroll
    for (int j = 0; j < 4; ++j) rmc[j] = RM[n0 + wn + j * 16 + lid];
    uint4* Lq = (uint4*)(ws + LIST_OFF);
    #pragma unroll
    for (int i = 0; i < 4; ++i)
        #pragma unroll
        for (int reg = 0; reg < 4; ++reg) {
            int grow = m0 + wm + i * 16 + q * 4 + reg;
            uint2 rm = RM[grow];
            unsigned int trow = rm.x & 255u, rsb = rm.y;
            float rs0 = 0.f, rs1 = 0.f, rs2 = 0.f, msOA = 0.f, msG = 0.f;
            #pragma unroll
            for (int j = 0; j < 4; ++j) {
                int gcol = n0 + wn + j * 16 + lid;
                float x0 = a0[i][j][reg] * SC2;
                float x1 = a1[i][j][reg] * SC2;
                float x2 = a2[i][j][reg] * SC2;
                float e0 = exp2f(x0);
                float e1 = exp2f(x1);
                float e2 = exp2f(x2);
                if (gcol == grow) e0 = 0.f;   // ori diagonal excluded from sums
                rs0 += e0; rs1 += e1; rs2 += e2;
                if ((rmc[j].x & 255u) == trow) {
                    msOA += e0 + e2;
                    msG  += e1;
                    unsigned int slot = rsb + (rmc[j].x >> 8);
                    if (slot < LCAP)
                        Lq[slot] = make_uint4((unsigned)grow, __float_as_uint(x0),
                                              __float_as_uint(x1), __float_as_uint(x2));
                }
            }
            #pragma unroll
            for (int off = 1; off < 16; off <<= 1) {
                rs0 += __shfl_xor(rs0, off);
                rs1 += __shfl_xor(rs1, off);
                rs2 += __shfl_xor(rs2, off);
                msOA += __shfl_xor(msOA, off);
                msG  += __shfl_xor(msG, off);
            }
            if (lid == 0) {
                atomicAdd(&F[O_S + grow], rs0);
                atomicAdd(&F[O_S + Bn + grow], rs1);
                atomicAdd(&F[O_S + 2 * Bn + grow], rs2);
                atomicAdd(&F[O_SMOA + grow], msOA);
                atomicAdd(&F[O_SMG + grow], msG);
            }
        }
}

// ---- flat loss pass: inline denominators, scaled atomic into d_out ----
__launch_bounds__(256)
__global__ void loss_kernel(char* ws, float* out) {
    float* F = (float*)ws;
    const unsigned int* I = (const unsigned int*)ws;
    const uint4* L = (const uint4*)(ws + LIST_OFF);
    unsigned int n = I[O_P]; if (n > LCAP) n = LCAP;
    float a0 = 0.f, a1 = 0.f;
    unsigned int stride = gridDim.x * 256;
    for (unsigned int idx = blockIdx.x * 256 + threadIdx.x; idx < n; idx += stride) {
        uint4 en = L[idx];
        int i = (int)en.x;
        float son = F[O_S + i], sgen = F[O_S + Bn + i], saug = F[O_S + 2 * Bn + i];
        float dco = (son + saug - F[O_SMOA + i]) + sgen + EPSF;
        float dad = (sgen - F[O_SMG + i]) + saug + son + DG + EPSF;
        float eo = exp2f(__uint_as_float(en.y));
        float eg = exp2f(__uint_as_float(en.z));
        float ea = exp2f(__uint_as_float(en.w));
        a0 += -__logf(eg / (eg + dad) + EPSF);
        a1 += -__logf(eo / (eo + dco) + EPSF) - __logf(ea / (ea + dco) + EPSF);
    }
    #pragma unroll
    for (int off = 1; off < 64; off <<= 1) { a0 += __shfl_xor(a0, off); a1 += __shfl_xor(a1, off); }
    __shared__ float r0[4], r1[4];
    int tid = threadIdx.x;
    if ((tid & 63) == 0) { r0[tid >> 6] = a0; r1[tid >> 6] = a1; }
    __syncthreads();
    if (tid == 0) {
        atomicAdd(&out[0], (r0[0] + r0[1] + r0[2] + r0[3]) * (1.0f / Bn));  // ad_loss
        atomicAdd(&out[1], (r1[0] + r1[1] + r1[2] + r1[3]) * (1.0f / Bn));  // co_loss
    }
}

extern "C" void kernel_launch(void* const* d_in, const int* in_sizes, int n_in,
                              void* d_out, int out_size, void* d_ws, size_t ws_size,
                              hipStream_t stream) {
    const float* f0 = (const float*)d_in[0];
    const float* f1 = (const float*)d_in[1];
    const float* f2 = (const float*)d_in[2];
    const int* tg = (const int*)d_in[3];
    char* ws = (char*)d_ws;
    unsigned int* I = (unsigned int*)d_ws;
    unsigned short* nb = (unsigned short*)(ws + NB_OFF);
    float* out = (float*)d_out;

    norm_kernel<<<dim3(Bn, 3), 256, 0, stream>>>(f0, f1, f2, nb);
    sort_kernel<<<1, 1024, 0, stream>>>(tg, I, out);
    gemm_rowsum<<<dim3(1024), 256, 0, stream>>>(nb, ws);
    loss_kernel<<<256, 256, 0, stream>>>(ws, out);
}